// Round 8
// baseline (254.310 us; speedup 1.0000x reference)
//
#include <hip/hip_runtime.h>
#include <math.h>
#include <stdint.h>

#define BB 2
#define SS 2048
#define DD 512
#define HH 1024
#define MMETA 64
#define KCONV 4
#define NHH 8
#define DHH 64
#define WINN 256
#define TT (MMETA + SS)     // 2112
#define BT (BB * TT)        // 4224
#define QKV_N 1536

typedef __attribute__((ext_vector_type(8))) short short8v;   // 8 bf16 = 4 VGPR
typedef __attribute__((ext_vector_type(4))) float f32x4;

__device__ __forceinline__ unsigned short f2bf(float f) {
    union { float f; unsigned u; } c; c.f = f;
    unsigned u = c.u;
    unsigned r = (u + 0x7fffu + ((u >> 16) & 1u)) >> 16;   // RNE
    return (unsigned short)r;
}
__device__ __forceinline__ float bf2f(unsigned short h) {
    union { unsigned u; float f; } c; c.u = ((unsigned)h) << 16;
    return c.f;
}

__device__ __forceinline__ void gload_lds16(const void* g, void* l) {
    __builtin_amdgcn_global_load_lds(
        (const __attribute__((address_space(1))) unsigned int*)g,
        (__attribute__((address_space(3))) unsigned int*)l, 16, 0, 0);
}

// counted vmcnt wait (T4)
template<int N>
__device__ __forceinline__ void vm_wait() {
    if constexpr (N == 0)      asm volatile("s_waitcnt vmcnt(0)" ::: "memory");
    else if constexpr (N == 4) asm volatile("s_waitcnt vmcnt(4)" ::: "memory");
    else if constexpr (N == 6) asm volatile("s_waitcnt vmcnt(6)" ::: "memory");
    else if constexpr (N == 8) asm volatile("s_waitcnt vmcnt(8)" ::: "memory");
    else static_assert(N == 0, "unsupported vmcnt");
}

// ---------------------------------------------------------------------------
// mega weight transpose+split: all 9 weights in one dispatch
// ---------------------------------------------------------------------------
struct WJobs {
    const float* W[9];
    unsigned short* Wh[9];
    unsigned short* Wl[9];
    int K[9];
    int N[9];
    int base[10];
};

__global__ __launch_bounds__(256) void wsplit_all_k(WJobs jb)
{
    __shared__ float tile[64][65];
    const int t = blockIdx.x;
    int j = 0;
    while (t >= jb.base[j + 1]) ++j;
    const int local = t - jb.base[j];
    const int K = jb.K[j], N = jb.N[j];
    const int nx = N >> 6;
    const int k0 = (local / nx) * 64, n0 = (local % nx) * 64;
    const float* W = jb.W[j];
    unsigned short* Wh = jb.Wh[j];
    unsigned short* Wl = jb.Wl[j];

    const int tid = threadIdx.x;
    #pragma unroll
    for (int i = 0; i < 16; ++i) {
        int lin = i * 256 + tid;
        int kr = lin >> 6, nc = lin & 63;
        tile[kr][nc] = W[(size_t)(k0 + kr) * N + n0 + nc];
    }
    __syncthreads();
    #pragma unroll
    for (int i = 0; i < 16; ++i) {
        int lin = i * 256 + tid;
        int nr = lin >> 6, kc = lin & 63;
        float v = tile[kc][nr];
        unsigned short hi = f2bf(v);
        size_t idx = (size_t)(n0 + nr) * K + k0 + kc;
        Wh[idx] = hi;
        Wl[idx] = f2bf(v - bf2f(hi));
    }
}

// ---------------------------------------------------------------------------
__global__ __launch_bounds__(256) void bias_concat_k(
    const float* __restrict__ bq, const float* __restrict__ bk,
    const float* __restrict__ bv, float* __restrict__ o)
{
    int i = blockIdx.x * 256 + threadIdx.x;
    if (i >= QKV_N) return;
    float v;
    if (i < 512) v = bq[i];
    else if (i < 1024) v = bk[i - 512];
    else v = bv[i - 1024];
    o[i] = v;
}

// ---------------------------------------------------------------------------
__global__ __launch_bounds__(256) void build_xm_k(
    const float* __restrict__ x, const float* __restrict__ meta,
    unsigned short* __restrict__ xh, unsigned short* __restrict__ xl)
{
    int idx = blockIdx.x * 256 + threadIdx.x;   // float4 index over BT*128
    if (idx >= BT * 128) return;
    int row = idx >> 7, c4 = idx & 127;
    int b = row >= TT;
    int t = row - b * TT;
    float4 v = (t < MMETA) ? ((const float4*)(meta + (size_t)t * DD))[c4]
                           : ((const float4*)(x + ((size_t)b * SS + (t - MMETA)) * DD))[c4];
    ushort4 h, lo;
    h.x = f2bf(v.x); lo.x = f2bf(v.x - bf2f(h.x));
    h.y = f2bf(v.y); lo.y = f2bf(v.y - bf2f(h.y));
    h.z = f2bf(v.z); lo.z = f2bf(v.z - bf2f(h.z));
    h.w = f2bf(v.w); lo.w = f2bf(v.w - bf2f(h.w));
    ((ushort4*)xh)[idx] = h;
    ((ushort4*)xl)[idx] = lo;
}

// ---------------------------------------------------------------------------
// bf16x3 MFMA GEMM, counted-vmcnt double-buffer, 2x2 waves.
//   BM in {64,128}, BN=128; wave tile (BM/2)x64; reads/MFMA = 2(MF+NF)/(3 MF NF)
//   EPI: 0 bias->fp32; 1 silu->hi/lo; 2 res+silu->hi/lo;
//        4 bias->hi/lo cols<1024, transposed vt write cols>=1024
// ---------------------------------------------------------------------------
template<int BM, int BN, int GN, int EPI, bool DROPMETA>
__global__ __launch_bounds__(256, 2) void gemm_mfma_k(
    const unsigned short* __restrict__ Ah, const unsigned short* __restrict__ Al,
    const unsigned short* __restrict__ Wh, const unsigned short* __restrict__ Wl,
    const float* __restrict__ bias,
    const unsigned short* __restrict__ resh, const unsigned short* __restrict__ resl,
    float* __restrict__ outf, unsigned short* __restrict__ outh,
    unsigned short* __restrict__ outl,
    unsigned short* __restrict__ vth, unsigned short* __restrict__ vtl,
    int K, int N)
{
    constexpr int MF = BM / 32;
    constexpr int NF = BN / 32;
    constexpr int ABYTES = BM * 64;
    constexpr int BBYTES = BN * 64;
    constexpr int BUFB = 2 * ABYTES + 2 * BBYTES;
    constexpr int LOADS = BUFB / 4096;    // per-thread loads per stage
    __shared__ short8v smem_v[(2 * BUFB) / 16];
    char* smem = (char*)smem_v;

    // bijective XCD-chunk swizzle (m204)
    constexpr int NWG = (BT / BM) * GN;
    constexpr int qch = NWG / 8, rch = NWG % 8;
    const int orig = blockIdx.x;
    const int xcd = orig & 7;
    const int swz = (xcd < rch ? xcd * (qch + 1) : rch * (qch + 1) + (xcd - rch) * qch)
                    + (orig >> 3);
    const int row0 = (swz / GN) * BM;
    const int n0 = (swz % GN) * BN;

    const int tid = threadIdx.x;
    const int l = tid & 63, wid = tid >> 6;
    const int wm = wid >> 1, wn = wid & 1;
    const int lr = l & 15, lg = l >> 4;

    const char* Ahg0 = (const char*)Ah + (size_t)row0 * K * 2;
    const char* Alg0 = (const char*)Al + (size_t)row0 * K * 2;
    const char* Whg  = (const char*)Wh + (size_t)n0 * K * 2;
    const char* Wlg  = (const char*)Wl + (size_t)n0 * K * 2;

    // conflict-free swizzle: sigma(r) = (r>>1)&3 over the 4 16B segs of a row
    int a_off[MF], b_off[NF];
    #pragma unroll
    for (int mf = 0; mf < MF; ++mf) {
        int r = wm * (BM / 2) + mf * 16 + lr;
        a_off[mf] = r * 64 + ((lg * 16) ^ (((r >> 1) & 3) << 4));
    }
    #pragma unroll
    for (int nf = 0; nf < NF; ++nf) {
        int r = wn * (BN / 2) + nf * 16 + lr;
        b_off[nf] = r * 64 + ((lg * 16) ^ (((r >> 1) & 3) << 4));
    }

    f32x4 acc[MF][NF];
    #pragma unroll
    for (int mf = 0; mf < MF; ++mf)
        #pragma unroll
        for (int nf = 0; nf < NF; ++nf) acc[mf][nf] = (f32x4){0.f, 0.f, 0.f, 0.f};

    const int NT = K / 32;

    auto stage = [&](int buf, int t) {
        char* lb = smem + buf * BUFB;
        const size_t kb = (size_t)t * 64;
        #pragma unroll
        for (int it = 0; it < ABYTES / 4096; ++it) {
            int off = (it * 256 + tid) * 16;
            int row = off >> 6;
            int sc = (off & 63) ^ (((row >> 1) & 3) << 4);
            size_t gb = (size_t)row * (K * 2) + kb + sc;
            gload_lds16(Ahg0 + gb, lb + off);
            gload_lds16(Alg0 + gb, lb + ABYTES + off);
        }
        #pragma unroll
        for (int it = 0; it < BBYTES / 4096; ++it) {
            int off = (it * 256 + tid) * 16;
            int row = off >> 6;
            int sc = (off & 63) ^ (((row >> 1) & 3) << 4);
            size_t gb = (size_t)row * (K * 2) + kb + sc;
            gload_lds16(Whg + gb, lb + 2 * ABYTES + off);
            gload_lds16(Wlg + gb, lb + 2 * ABYTES + BBYTES + off);
        }
    };

    stage(0, 0);

    int cur = 0;
    for (int t = 0; t < NT; ++t) {
        if (t + 1 < NT) {
            stage(cur ^ 1, t + 1);
            vm_wait<LOADS>();        // wait only tile t's loads; t+1 stays in flight
        } else {
            vm_wait<0>();
        }
        __builtin_amdgcn_s_barrier();
        __builtin_amdgcn_sched_barrier(0);

        char* lb = smem + cur * BUFB;
        short8v ah[MF], al[MF], bh[NF], bl[NF];
        #pragma unroll
        for (int mf = 0; mf < MF; ++mf) {
            ah[mf] = *(const short8v*)(lb + a_off[mf]);
            al[mf] = *(const short8v*)(lb + ABYTES + a_off[mf]);
        }
        #pragma unroll
        for (int nf = 0; nf < NF; ++nf) {
            bh[nf] = *(const short8v*)(lb + 2 * ABYTES + b_off[nf]);
            bl[nf] = *(const short8v*)(lb + 2 * ABYTES + BBYTES + b_off[nf]);
        }
        __builtin_amdgcn_s_setprio(1);
        #pragma unroll
        for (int mf = 0; mf < MF; ++mf)
            #pragma unroll
            for (int nf = 0; nf < NF; ++nf) {
                acc[mf][nf] = __builtin_amdgcn_mfma_f32_16x16x32_bf16(ah[mf], bh[nf], acc[mf][nf], 0, 0, 0);
                acc[mf][nf] = __builtin_amdgcn_mfma_f32_16x16x32_bf16(ah[mf], bl[nf], acc[mf][nf], 0, 0, 0);
                acc[mf][nf] = __builtin_amdgcn_mfma_f32_16x16x32_bf16(al[mf], bh[nf], acc[mf][nf], 0, 0, 0);
            }
        __builtin_amdgcn_s_setprio(0);
        __builtin_amdgcn_s_barrier();    // reads of buf[cur] done before overwrite
        cur ^= 1;
    }

    // epilogue: C/D layout col = lane&15, row = (lane>>4)*4 + reg
    #pragma unroll
    for (int mf = 0; mf < MF; ++mf) {
        #pragma unroll
        for (int nf = 0; nf < NF; ++nf) {
            int col = n0 + wn * (BN / 2) + nf * 16 + lr;
            float bv = bias[col];
            if (EPI == 4 && col >= 1024) {
                unsigned short hv[4], lv[4];
                #pragma unroll
                for (int j = 0; j < 4; ++j) {
                    float v = acc[mf][nf][j] + bv;
                    unsigned short hi = f2bf(v);
                    hv[j] = hi; lv[j] = f2bf(v - bf2f(hi));
                }
                int dg = col - 1024;
                size_t tok = (size_t)row0 + wm * (BM / 2) + mf * 16 + lg * 4;
                *(ushort4*)(vth + (size_t)dg * BT + tok) = *(ushort4*)hv;
                *(ushort4*)(vtl + (size_t)dg * BT + tok) = *(ushort4*)lv;
            } else {
                #pragma unroll
                for (int j = 0; j < 4; ++j) {
                    int row = row0 + wm * (BM / 2) + mf * 16 + lg * 4 + j;
                    float v = acc[mf][nf][j] + bv;
                    if (EPI == 1 || EPI == 2) v = v / (1.f + __expf(-v));
                    size_t idx = (size_t)row * N + col;
                    if (EPI == 2) v += bf2f(resh[idx]) + bf2f(resl[idx]);
                    if (EPI == 0) {
                        if (DROPMETA) {
                            int b = row >= TT;
                            int t2 = row - b * TT;
                            if (t2 >= MMETA)
                                outf[((size_t)b * SS + (t2 - MMETA)) * N + col] = v;
                        } else {
                            outf[idx] = v;
                        }
                    } else {
                        unsigned short hi = f2bf(v);
                        outh[idx] = hi;
                        outl[idx] = f2bf(v - bf2f(hi));
                    }
                }
            }
        }
    }
}

// ---------------------------------------------------------------------------
__global__ __launch_bounds__(256) void conv_norm_k(
    const float* __restrict__ qlin, const float* __restrict__ convw,
    unsigned short* __restrict__ qh, unsigned short* __restrict__ ql)
{
    const int row = blockIdx.x;
    const int b = row >= TT;
    const int t = row - b * TT;
    const int tid = threadIdx.x;

    float vals[2];
    float ss = 0.f;
    #pragma unroll
    for (int e = 0; e < 2; ++e) {
        int d = tid + e * 256;
        float acc = 0.f;
        #pragma unroll
        for (int k = 0; k < KCONV; ++k) {
            int tt = t - (KCONV - 1) + k;
            if (tt >= 0)
                acc += qlin[((size_t)b * TT + tt) * DD + d] * convw[k * DD + d];
        }
        vals[e] = acc;
        ss += acc * acc;
    }
    #pragma unroll
    for (int off = 32; off > 0; off >>= 1)
        ss += __shfl_xor(ss, off);
    __shared__ float red[4];
    if ((tid & 63) == 0) red[tid >> 6] = ss;
    __syncthreads();
    float total = red[0] + red[1] + red[2] + red[3];
    float inv = 1.f / fmaxf(sqrtf(total), 1e-12f);
    #pragma unroll
    for (int e = 0; e < 2; ++e) {
        int d = tid + e * 256;
        float v = vals[e] * inv;
        unsigned short hi = f2bf(v);
        qh[(size_t)row * DD + d] = hi;
        ql[(size_t)row * DD + d] = f2bf(v - bf2f(hi));
    }
}

// ---------------------------------------------------------------------------
// Flash sliding-window attention, MFMA, V^T staged from global.
// ---------------------------------------------------------------------------
__global__ __launch_bounds__(256, 2) void swa_flash_k(
    const unsigned short* __restrict__ qkvh, const unsigned short* __restrict__ qkvl,
    const unsigned short* __restrict__ vth, const unsigned short* __restrict__ vtl,
    unsigned short* __restrict__ oh, unsigned short* __restrict__ ol)
{
    // LDS: Kh 8192 | Kl 8192 | Vh 8192 | Vl 8192 | P 4x2304
    __shared__ short8v lds_v[41984 / 16];
    char* lds = (char*)lds_v;
    char* Kh_lds = lds;
    char* Kl_lds = lds + 8192;
    char* Vh_lds = lds + 16384;
    char* Vl_lds = lds + 24576;
    char* P_lds  = lds + 32768;

    const int tid = threadIdx.x;
    const int lane = tid & 63, w = tid >> 6;
    const int l15 = lane & 15, lg = lane >> 4;
    const int q0 = blockIdx.x * 64;
    const int h = blockIdx.y, b = blockIdx.z;
    const int rowbase = b * TT;

    const int qrow = rowbase + q0 + w * 16 + l15;
    short8v qhf[2], qlf[2];
    #pragma unroll
    for (int kh = 0; kh < 2; ++kh) {
        size_t off = (size_t)qrow * QKV_N + h * 64 + kh * 32 + lg * 8;
        qhf[kh] = *(const short8v*)(qkvh + off);
        qlf[kh] = *(const short8v*)(qkvl + off);
    }

    f32x4 o_acc[4];
    #pragma unroll
    for (int td = 0; td < 4; ++td) o_acc[td] = (f32x4){0.f, 0.f, 0.f, 0.f};
    float m_r[4], l_r[4];
    #pragma unroll
    for (int r = 0; r < 4; ++r) { m_r[r] = -1e30f; l_r[r] = 0.f; }

    char* Pw = P_lds + w * 2304;   // per-wave [16][72] bf16

    for (int kt = 0; kt < 5; ++kt) {
        const int kst = q0 - 256 + kt * 64;
        if (kst + 64 <= 0) continue;
        __syncthreads();
        #pragma unroll
        for (int it = 0; it < 2; ++it) {
            int lin = it * 256 + tid;
            int r = lin >> 3, seg = lin & 7;
            int colb = (seg * 16) ^ ((r & 7) << 4);
            size_t gb = ((size_t)(rowbase + kst + r) * QKV_N + 512 + h * 64) * 2 + colb;
            gload_lds16((const char*)qkvh + gb, Kh_lds + lin * 16);
            gload_lds16((const char*)qkvl + gb, Kl_lds + lin * 16);
        }
        #pragma unroll
        for (int it = 0; it < 2; ++it) {
            int lin = it * 256 + tid;
            int dd = lin >> 3, seg = lin & 7;
            int colb = (seg * 16) ^ ((dd & 7) << 4);
            size_t gb = ((size_t)(h * 64 + dd) * BT + rowbase + kst) * 2 + colb;
            gload_lds16((const char*)vth + gb, Vh_lds + lin * 16);
            gload_lds16((const char*)vtl + gb, Vl_lds + lin * 16);
        }
        __syncthreads();

        f32x4 s_fr[4];
        #pragma unroll
        for (int tj = 0; tj < 4; ++tj) s_fr[tj] = (f32x4){0.f, 0.f, 0.f, 0.f};
        #pragma unroll
        for (int tj = 0; tj < 4; ++tj) {
            int j = tj * 16 + l15;
            #pragma unroll
            for (int kh = 0; kh < 2; ++kh) {
                int colb = (kh * 64 + lg * 16) ^ ((j & 7) << 4);
                short8v kbh = *(const short8v*)(Kh_lds + j * 128 + colb);
                short8v kbl = *(const short8v*)(Kl_lds + j * 128 + colb);
                s_fr[tj] = __builtin_amdgcn_mfma_f32_16x16x32_bf16(qhf[kh], kbh, s_fr[tj], 0, 0, 0);
                s_fr[tj] = __builtin_amdgcn_mfma_f32_16x16x32_bf16(qhf[kh], kbl, s_fr[tj], 0, 0, 0);
                s_fr[tj] = __builtin_amdgcn_mfma_f32_16x16x32_bf16(qlf[kh], kbh, s_fr[tj], 0, 0, 0);
            }
        }
        #pragma unroll
        for (int tj = 0; tj < 4; ++tj) {
            int j = kst + tj * 16 + l15;
            #pragma unroll
            for (int r = 0; r < 4; ++r) {
                int i = q0 + w * 16 + lg * 4 + r;
                bool valid = (j <= i) && (i - j < WINN);
                s_fr[tj][r] = valid ? s_fr[tj][r] * 0.125f : -1e30f;
            }
        }
        float mx[4];
        #pragma unroll
        for (int r = 0; r < 4; ++r) {
            mx[r] = fmaxf(fmaxf(s_fr[0][r], s_fr[1][r]), fmaxf(s_fr[2][r], s_fr[3][r]));
            #pragma unroll
            for (int msk = 1; msk <= 8; msk <<= 1)
                mx[r] = fmaxf(mx[r], __shfl_xor(mx[r], msk));
            float mn = fmaxf(m_r[r], mx[r]);
            float sc = __expf(m_r[r] - mn);
            m_r[r] = mn;
            l_r[r] *= sc;
            #pragma unroll
            for (int td = 0; td < 4; ++td) o_acc[td][r] *= sc;
        }
        float rs[4] = {0.f, 0.f, 0.f, 0.f};
        #pragma unroll
        for (int tj = 0; tj < 4; ++tj) {
            #pragma unroll
            for (int r = 0; r < 4; ++r) {
                float p = __expf(s_fr[tj][r] - m_r[r]);
                rs[r] += p;
                ((unsigned short*)Pw)[(lg * 4 + r) * 72 + tj * 16 + l15] = f2bf(p);
            }
        }
        #pragma unroll
        for (int r = 0; r < 4; ++r) {
            #pragma unroll
            for (int msk = 1; msk <= 8; msk <<= 1)
                rs[r] += __shfl_xor(rs[r], msk);
            l_r[r] += rs[r];
        }
        short8v pa[2];
        #pragma unroll
        for (int jh = 0; jh < 2; ++jh)
            pa[jh] = *(const short8v*)(Pw + l15 * 144 + jh * 64 + lg * 16);
        #pragma unroll
        for (int td = 0; td < 4; ++td) {
            int drow = td * 16 + l15;
            #pragma unroll
            for (int jh = 0; jh < 2; ++jh) {
                int colb = (jh * 64 + lg * 16) ^ ((drow & 7) << 4);
                short8v vfh = *(const short8v*)(Vh_lds + drow * 128 + colb);
                short8v vfl = *(const short8v*)(Vl_lds + drow * 128 + colb);
                o_acc[td] = __builtin_amdgcn_mfma_f32_16x16x32_bf16(pa[jh], vfh, o_acc[td], 0, 0, 0);
                o_acc[td] = __builtin_amdgcn_mfma_f32_16x16x32_bf16(pa[jh], vfl, o_acc[td], 0, 0, 0);
            }
        }
    }

    #pragma unroll
    for (int r = 0; r < 4; ++r) {
        float inv = 1.f / l_r[r];
        int row = rowbase + q0 + w * 16 + lg * 4 + r;
        #pragma unroll
        for (int td = 0; td < 4; ++td) {
            float v = o_acc[td][r] * inv;
            size_t idx = (size_t)row * DD + h * 64 + td * 16 + l15;
            unsigned short hi = f2bf(v);
            oh[idx] = hi;
            ol[idx] = f2bf(v - bf2f(hi));
        }
    }
}

// ---------------------------------------------------------------------------
// Launch
// ---------------------------------------------------------------------------
extern "C" void kernel_launch(void* const* d_in, const int* in_sizes, int n_in,
                              void* d_out, int out_size, void* d_ws, size_t ws_size,
                              hipStream_t stream)
{
    const float* x       = (const float*)d_in[0];
    const float* meta    = (const float*)d_in[1];
    const float* qp_w    = (const float*)d_in[2];
    const float* qp_b    = (const float*)d_in[3];
    const float* qp_conv = (const float*)d_in[4];
    const float* w_in    = (const float*)d_in[5];
    const float* b_in    = (const float*)d_in[6];
    const float* w_hid   = (const float*)d_in[7];
    const float* b_hid   = (const float*)d_in[8];
    const float* w_out   = (const float*)d_in[9];
    const float* b_out   = (const float*)d_in[10];
    const float* wq      = (const float*)d_in[11];
    const float* bq      = (const float*)d_in[12];
    const float* wk      = (const float*)d_in[13];
    const float* bk      = (const float*)d_in[14];
    const float* wv      = (const float*)d_in[15];
    const float* bv      = (const float*)d_in[16];
    const float* wo      = (const float*)d_in[17];
    const float* bo      = (const float*)d_in[18];
    float* out = (float*)d_out;

    typedef unsigned short us;
    char* p = (char*)d_ws;
    auto alloc = [&](size_t n) { char* r = p; p += (n + 255) & ~(size_t)255; return r; };

    us* wqp_h   = (us*)alloc(512 * 512 * 2);   us* wqp_l   = (us*)alloc(512 * 512 * 2);
    us* win_h   = (us*)alloc(512 * 1024 * 2);  us* win_l   = (us*)alloc(512 * 1024 * 2);
    us* whid0_h = (us*)alloc(1024 * 1024 * 2); us* whid0_l = (us*)alloc(1024 * 1024 * 2);
    us* whid1_h = (us*)alloc(1024 * 1024 * 2); us* whid1_l = (us*)alloc(1024 * 1024 * 2);
    us* wout_h  = (us*)alloc(1024 * 512 * 2);  us* wout_l  = (us*)alloc(1024 * 512 * 2);
    us* wqkv_h  = (us*)alloc((size_t)QKV_N * 512 * 2);
    us* wqkv_l  = (us*)alloc((size_t)QKV_N * 512 * 2);
    us* wo_h    = (us*)alloc(512 * 512 * 2);   us* wo_l    = (us*)alloc(512 * 512 * 2);
    float* bqkv = (float*)alloc(QKV_N * 4);

    const size_t HALF = (size_t)BT * 512 * 2;   // 4.3 MB
    char* RA = alloc(2 * HALF);   // xm hi/lo  -> later ob hi/lo
    char* RB = alloc(2 * HALF);   // qlin fp32
    char* RC = alloc(2 * HALF);   // qn hi/lo -> r hi/lo
    char* RD = alloc(6 * HALF);   // ha hi/lo -> hc hi/lo -> qkv hi/lo (q,k only)
    char* RE = alloc(4 * HALF);   // hb hi/lo -> vt hi/lo ([512][BT] each)

    us* xm_h = (us*)RA;   us* xm_l = (us*)(RA + HALF);
    float* qlin = (float*)RB;
    us* qn_h = (us*)RC;   us* qn_l = (us*)(RC + HALF);
    us* ha_h = (us*)RD;   us* ha_l = (us*)(RD + 2 * HALF);
    us* hb_h = (us*)RE;   us* hb_l = (us*)(RE + 2 * HALF);
    us* hc_h = ha_h;      us* hc_l = ha_l;
    us* r_h  = qn_h;      us* r_l  = qn_l;
    us* qkv_h = (us*)RD;  us* qkv_l = (us*)(RD + 3 * HALF);
    us* vt_h  = (us*)RE;  us* vt_l  = (us*)(RE + HALF);
    us* ob_h = (us*)RA;   us* ob_l = (us*)(RA + HALF);

    // --- weight prep: one mega dispatch ---
    WJobs jb;
    const float* Ws[9]   = {qp_w, w_in, w_hid, w_hid + (size_t)1024 * 1024, w_out,
                            wq, wk, wv, wo};
    us* Whs[9] = {wqp_h, win_h, whid0_h, whid1_h, wout_h,
                  wqkv_h, wqkv_h + 512 * 512, wqkv_h + 2 * 512 * 512, wo_h};
    us* Wls[9] = {wqp_l, win_l, whid0_l, whid1_l, wout_l,
                  wqkv_l, wqkv_l + 512 * 512, wqkv_l + 2 * 512 * 512, wo_l};
    int Ks[9] = {512, 512, 1024, 1024, 1024, 512, 512, 512, 512};
    int Ns[9] = {512, 1024, 1024, 1024, 512, 512, 512, 512, 512};
    int acc_t = 0;
    for (int j = 0; j < 9; ++j) {
        jb.W[j] = Ws[j]; jb.Wh[j] = Whs[j]; jb.Wl[j] = Wls[j];
        jb.K[j] = Ks[j]; jb.N[j] = Ns[j];
        jb.base[j] = acc_t;
        acc_t += (Ks[j] / 64) * (Ns[j] / 64);
    }
    jb.base[9] = acc_t;    // 1088
    wsplit_all_k<<<acc_t, 256, 0, stream>>>(jb);
    bias_concat_k<<<6, 256, 0, stream>>>(bq, bk, bv, bqkv);

    // --- pipeline ---
    build_xm_k<<<(BT * 128 + 255) / 256, 256, 0, stream>>>(x, meta, xm_h, xm_l);

    // qlin = xm @ qp_w + b (fp32 out): 64x128 tile, grid 264
    gemm_mfma_k<64, 128, 4, 0, false><<<264, 256, 0, stream>>>(
        xm_h, xm_l, wqp_h, wqp_l, qp_b, nullptr, nullptr, qlin, nullptr, nullptr, nullptr, nullptr, 512, 512);
    conv_norm_k<<<BT, 256, 0, stream>>>(qlin, qp_conv, qn_h, qn_l);
    // ha = silu(qn @ w_in + b_in): 128x128, grid 264
    gemm_mfma_k<128, 128, 8, 1, false><<<264, 256, 0, stream>>>(
        qn_h, qn_l, win_h, win_l, b_in, nullptr, nullptr, nullptr, ha_h, ha_l, nullptr, nullptr, 512, 1024);
    gemm_mfma_k<128, 128, 8, 2, false><<<264, 256, 0, stream>>>(
        ha_h, ha_l, whid0_h, whid0_l, b_hid, ha_h, ha_l, nullptr, hb_h, hb_l, nullptr, nullptr, 1024, 1024);
    gemm_mfma_k<128, 128, 8, 2, false><<<264, 256, 0, stream>>>(
        hb_h, hb_l, whid1_h, whid1_l, b_hid + HH, hb_h, hb_l, nullptr, hc_h, hc_l, nullptr, nullptr, 1024, 1024);
    // r = silu(hc @ w_out + b_out): 64x128, grid 264
    gemm_mfma_k<64, 128, 4, 1, false><<<264, 256, 0, stream>>>(
        hc_h, hc_l, wout_h, wout_l, b_out, nullptr, nullptr, nullptr, r_h, r_l, nullptr, nullptr, 1024, 512);
    // fused q/k/v projection: 128x128, grid 396
    gemm_mfma_k<128, 128, 12, 4, false><<<396, 256, 0, stream>>>(
        r_h, r_l, wqkv_h, wqkv_l, bqkv, nullptr, nullptr, nullptr, qkv_h, qkv_l, vt_h, vt_l, 512, QKV_N);
    // flash sliding-window attention
    swa_flash_k<<<dim3(TT / 64, NHH, BB), 256, 0, stream>>>(qkv_h, qkv_l, vt_h, vt_l, ob_h, ob_l);
    // out = (ob @ wo + bo)[t >= M]: 64x128, grid 264
    gemm_mfma_k<64, 128, 4, 0, true><<<264, 256, 0, stream>>>(
        ob_h, ob_l, wo_h, wo_l, bo, nullptr, nullptr, out, nullptr, nullptr, nullptr, nullptr, 512, 512);
}